// Round 5
// baseline (47.757 us; speedup 1.0000x reference)
//
#include <hip/hip_runtime.h>
#include <hip/hip_bf16.h>

#define NB 8
#define NS 4096
#define NH 1152
#define LEN 256
#define WPB 128                      // worker blocks per batch (grid = 8*128 = 1024)
#define CAP 256                      // rows[] fast-path capacity

typedef float vf4 __attribute__((ext_vector_type(4)));

// Fused pooler with dynamic work queue.
// Grid = 1024 blocks (half of residency capacity) so the per-batch atomic
// queue rebalances segment work across CUs (static 2048-block grid was
// straggler-CU-bound: runtime = max over CUs of sum of 8 Binomial counts,
// ~+29% over mean -- matched observed 31.9us vs 24.6us ideal).
// Phase 1 (once per block): scan own batch's 32KB patch coords (L2-hot),
// keep packed coords in 16 VGPRs. Per item: re-derive the segment's row
// list from registers (~100cy), stream-sum rows, write output row.
__global__ __launch_bounds__(256) void gvp_fused(
        const float* __restrict__ hidden,
        const int* __restrict__ patch,
        int* __restrict__ qcnt,            // [NB], pre-zeroed by memset
        float* __restrict__ out,
        float* __restrict__ maskout) {
    int w = blockIdx.x;
    int b = w / WPB;
    int t = threadIdx.x;                   // 256 threads
    int l = t & 31;
    int grp = t >> 5;                      // 8 tail groups

    __shared__ int rows[CAP];
    __shared__ vf4 s_red[256];
    __shared__ int s_max[4];
    __shared__ int s_cnt, s_q, s_mult;

    // ---- Phase 1: scan batch once; coords stay in registers ----
    const int2* p2 = (const int2*)(patch + (size_t)b * NS * 2);
    int pk[16];
    int m = 0;
    #pragma unroll
    for (int i = 0; i < 16; ++i) {
        int2 v = p2[t + 256 * i];
        int x = v.x < 0 ? 0 : v.x;
        int y = v.y < 0 ? 0 : v.y;
        pk[i] = x | (y << 16);
        m = max(m, x);
    }
    #pragma unroll
    for (int off = 32; off > 0; off >>= 1)
        m = max(m, __shfl_down(m, off, 64));
    if ((t & 63) == 0) s_max[t >> 6] = m;
    __syncthreads();
    if (t == 0)
        s_mult = (max(max(s_max[0], s_max[1]), max(s_max[2], s_max[3])) + 1) >> 2;
    __syncthreads();
    int mult = s_mult;

    const float scale = 2.1213203435596424f;   // sqrt(1152) / 16
    const float* hb = hidden + (size_t)b * NS * NH;

    int q = w & (WPB - 1);                 // static first item; rest dynamic
    while (q < LEN) {
        vf4 a0 = 0.f, a1 = 0.f, a2 = 0.f;

        auto gather = [&](int n) {         // sum rows[0..n): cols 0-255 -> t,
            int r = 0;                     // tail cols 256-287 -> round-robin
            for (; r + 7 < n; r += 8) {
                const vf4* p0 = (const vf4*)(hb + (size_t)rows[r + 0] * NH);
                const vf4* p1 = (const vf4*)(hb + (size_t)rows[r + 1] * NH);
                const vf4* p2r = (const vf4*)(hb + (size_t)rows[r + 2] * NH);
                const vf4* p3 = (const vf4*)(hb + (size_t)rows[r + 3] * NH);
                const vf4* p4 = (const vf4*)(hb + (size_t)rows[r + 4] * NH);
                const vf4* p5 = (const vf4*)(hb + (size_t)rows[r + 5] * NH);
                const vf4* p6 = (const vf4*)(hb + (size_t)rows[r + 6] * NH);
                const vf4* p7 = (const vf4*)(hb + (size_t)rows[r + 7] * NH);
                vf4 v0 = p0[t], v1 = p1[t], v2 = p2r[t], v3 = p3[t];
                vf4 v4 = p4[t], v5 = p5[t], v6 = p6[t], v7 = p7[t];
                v0 += v1; v2 += v3; v4 += v5; v6 += v7;
                v0 += v2; v4 += v6;
                a0 += v0; a1 += v4;
            }
            for (; r < n; ++r)
                a0 += ((const vf4*)(hb + (size_t)rows[r] * NH))[t];
            for (int r2 = grp; r2 < n; r2 += 8)
                a2 += ((const vf4*)(hb + (size_t)rows[r2] * NH))[256 + l];
        };

        // build row list for segment q from registers
        if (t == 0) s_cnt = 0;
        __syncthreads();
        #pragma unroll
        for (int i = 0; i < 16; ++i) {
            int x = pk[i] & 0xffff, y = pk[i] >> 16;
            int seg = (x >> 2) + mult * (y >> 2);
            if (seg == q) {
                int pos = atomicAdd(&s_cnt, 1);
                if (pos < CAP) rows[pos] = t + 256 * i;
            }
        }
        __syncthreads();
        int cnt = s_cnt;

        if (cnt <= CAP) {
            gather(cnt);
        } else {
            // correctness-only slow path (impossible for the bench input):
            // window i holds positions [256i,256(i+1)) -> <=256 matches each
            for (int win = 0; win < 16; ++win) {
                __syncthreads();
                if (t == 0) s_cnt = 0;
                __syncthreads();
                int x = pk[win] & 0xffff, y = pk[win] >> 16;
                int seg = (x >> 2) + mult * (y >> 2);
                if (seg == q) rows[atomicAdd(&s_cnt, 1)] = t + 256 * win;
                __syncthreads();
                gather(s_cnt);
            }
        }

        a0 += a1;
        s_red[t] = a2;
        __syncthreads();

        int g = (b << 8) + q;
        vf4* og = (vf4*)(out + (size_t)g * NH);
        og[t] = a0 * scale;
        if (t < 32) {
            vf4 s = 0.f;
            #pragma unroll
            for (int j = 0; j < 8; ++j) s += s_red[j * 32 + t];
            og[256 + t] = s * scale;
        }
        if (t == 0) {
            maskout[g] = (cnt > 0) ? 1.0f : 0.0f;
            s_q = WPB + atomicAdd(&qcnt[b], 1);   // pop next item
        }
        __syncthreads();
        q = s_q;
    }
}

extern "C" void kernel_launch(void* const* d_in, const int* in_sizes, int n_in,
                              void* d_out, int out_size, void* d_ws, size_t ws_size,
                              hipStream_t stream) {
    const float* hidden = (const float*)d_in[0];
    const int*   patch  = (const int*)d_in[1];
    // d_in[2] (padding_positions) unused: S != LENGTH branch.
    float* out = (float*)d_out;
    float* maskout = out + (size_t)NB * LEN * NH;   // tuple: pooled then mask
    int* qcnt = (int*)d_ws;

    hipMemsetAsync(qcnt, 0, NB * sizeof(int), stream);
    gvp_fused<<<NB * WPB, 256, 0, stream>>>(hidden, patch, qcnt, out, maskout);
}

// Round 6
// 35.796 us; speedup vs baseline: 1.3341x; 1.3341x over previous
//
#include <hip/hip_runtime.h>
#include <hip/hip_bf16.h>

#define NB 8
#define NS 4096
#define NH 1152
#define LEN 256
#define NT 576                     // 9 waves; 1152 floats = 576 float2 exactly

typedef float vf2 __attribute__((ext_vector_type(2)));

// One block per (b, seg); 576 threads. Grid = 2048 blocks x 9 waves = 2.25x
// machine residency -> hardware dispatcher rebalances (R3's 2048x4 was
// exactly-resident: zero rebalancing, straggler-CU-bound at +28%).
// Phase 1: self-service prep from L2-resident patch coords (32 KB/batch).
// Phase 2: each thread owns exactly one float2 column -> perfectly uniform.
__global__ __launch_bounds__(NT) void gvp_fused(
        const float* __restrict__ hidden,
        const int* __restrict__ patch,
        float* __restrict__ out,
        float* __restrict__ maskout) {
    int g = blockIdx.x;                        // b*256 + seg
    int b = g >> 8;
    int myseg = g & (LEN - 1);
    int t = threadIdx.x;

    __shared__ int rows[NS];                   // worst case: all rows one seg
    __shared__ int s_max[9];
    __shared__ int s_cnt, s_mult;
    if (t == 0) s_cnt = 0;

    // ---- Phase 1: scan batch coords (L2-hot), coords stay in registers ----
    const int2* p2 = (const int2*)(patch + (size_t)b * NS * 2);
    int pk[8];
    int m = 0;
    #pragma unroll
    for (int i = 0; i < 7; ++i) {              // windows 0..6 full (7*576=4032)
        int2 v = p2[t + NT * i];
        int x = v.x < 0 ? 0 : v.x;
        int y = v.y < 0 ? 0 : v.y;
        pk[i] = x | (y << 16);                 // coords < 2^15: sign bit clear
        m = max(m, x);
    }
    pk[7] = -1;                                // sentinel: invalid
    if (t < NS - NT * 7) {                     // window 7 partial (64 valid)
        int2 v = p2[t + NT * 7];
        int x = v.x < 0 ? 0 : v.x;
        int y = v.y < 0 ? 0 : v.y;
        pk[7] = x | (y << 16);
        m = max(m, x);
    }
    #pragma unroll
    for (int off = 32; off > 0; off >>= 1)
        m = max(m, __shfl_down(m, off, 64));
    if ((t & 63) == 0) s_max[t >> 6] = m;
    __syncthreads();
    if (t == 0) {
        int mm = s_max[0];
        #pragma unroll
        for (int j = 1; j < 9; ++j) mm = max(mm, s_max[j]);
        s_mult = (mm + 1) >> 2;                // (max_x + 1) // k
    }
    __syncthreads();
    int mult = s_mult;

    #pragma unroll
    for (int i = 0; i < 8; ++i) {
        if (pk[i] >= 0) {
            int x = pk[i] & 0xffff, y = pk[i] >> 16;
            int seg = (x >> 2) + mult * (y >> 2);   // ref guarantees < LEN
            if (seg == myseg)
                rows[atomicAdd(&s_cnt, 1)] = t + NT * i;
        }
    }
    __syncthreads();
    int cnt = s_cnt;

    // ---- Phase 2: stream-sum; thread t = float2 column t, 8-row unroll ----
    const float* hb = hidden + (size_t)b * NS * NH;
    vf2 a0 = 0.f, a1 = 0.f;
    int r = 0;
    for (; r + 7 < cnt; r += 8) {
        vf2 v0 = ((const vf2*)(hb + (size_t)rows[r + 0] * NH))[t];
        vf2 v1 = ((const vf2*)(hb + (size_t)rows[r + 1] * NH))[t];
        vf2 v2 = ((const vf2*)(hb + (size_t)rows[r + 2] * NH))[t];
        vf2 v3 = ((const vf2*)(hb + (size_t)rows[r + 3] * NH))[t];
        vf2 v4 = ((const vf2*)(hb + (size_t)rows[r + 4] * NH))[t];
        vf2 v5 = ((const vf2*)(hb + (size_t)rows[r + 5] * NH))[t];
        vf2 v6 = ((const vf2*)(hb + (size_t)rows[r + 6] * NH))[t];
        vf2 v7 = ((const vf2*)(hb + (size_t)rows[r + 7] * NH))[t];
        v0 += v1; v2 += v3; v4 += v5; v6 += v7;
        v0 += v2; v4 += v6;
        a0 += v0; a1 += v4;
    }
    for (; r < cnt; ++r)
        a0 += ((const vf2*)(hb + (size_t)rows[r] * NH))[t];
    a0 += a1;

    const float scale = 2.1213203435596424f;   // sqrt(1152) / 16
    ((vf2*)(out + (size_t)g * NH))[t] = a0 * scale;
    if (t == 0) maskout[g] = (cnt > 0) ? 1.0f : 0.0f;
}

extern "C" void kernel_launch(void* const* d_in, const int* in_sizes, int n_in,
                              void* d_out, int out_size, void* d_ws, size_t ws_size,
                              hipStream_t stream) {
    const float* hidden = (const float*)d_in[0];
    const int*   patch  = (const int*)d_in[1];
    // d_in[2] (padding_positions) unused: S != LENGTH branch.
    float* out = (float*)d_out;
    float* maskout = out + (size_t)NB * LEN * NH;   // tuple: pooled then mask

    gvp_fused<<<NB * LEN, NT, 0, stream>>>(hidden, patch, out, maskout);
}

// Round 7
// 32.330 us; speedup vs baseline: 1.4772x; 1.1072x over previous
//
#include <hip/hip_runtime.h>
#include <hip/hip_bf16.h>

#define NB 8
#define NS 4096
#define NH 1152
#define LEN 256
#define NT 320                     // 5 waves/block; 2048 blocks x 5 = 10240 waves
                                   // = 1.25x residency -> dispatcher refill
#define NC 288                     // float4 columns per output row

typedef float vf4 __attribute__((ext_vector_type(4)));

// One block per (b, seg). Threads 0..287 own exactly one float4 column.
// Grid deliberately oversubscribes wave residency by 1.25x so CUs that drew
// light segments get refilled from the 512-block queue (R3/R4's exact-resident
// grid had zero refill -> runtime = max over CUs of 8 Binomial counts, +28%).
__global__ __launch_bounds__(NT) void gvp_fused(
        const float* __restrict__ hidden,
        const int* __restrict__ patch,
        float* __restrict__ out,
        float* __restrict__ maskout) {
    int g = blockIdx.x;                        // b*256 + seg
    int b = g >> 8;
    int myseg = g & (LEN - 1);
    int t = threadIdx.x;

    __shared__ int rows[NS];                   // worst case: all rows one seg
    __shared__ int s_max[5];
    __shared__ int s_cnt, s_mult;
    if (t == 0) s_cnt = 0;

    // ---- Phase 1: scan batch coords (int4 = 2 coords/load, L2-hot) ----
    const int4* p4 = (const int4*)(patch + (size_t)b * NS * 2);  // 2048 pairs
    int pk[14];
    int m = 0;
    #pragma unroll
    for (int w = 0; w < 6; ++w) {              // pairs [0, 1920)
        int4 v = p4[t + NT * w];
        int x0 = v.x < 0 ? 0 : v.x, y0 = v.y < 0 ? 0 : v.y;
        int x1 = v.z < 0 ? 0 : v.z, y1 = v.w < 0 ? 0 : v.w;
        pk[2 * w]     = x0 | (y0 << 16);
        pk[2 * w + 1] = x1 | (y1 << 16);
        m = max(m, max(x0, x1));
    }
    pk[12] = pk[13] = -1;                      // sentinel
    if (t < 128) {                             // pairs [1920, 2048)
        int4 v = p4[1920 + t];
        int x0 = v.x < 0 ? 0 : v.x, y0 = v.y < 0 ? 0 : v.y;
        int x1 = v.z < 0 ? 0 : v.z, y1 = v.w < 0 ? 0 : v.w;
        pk[12] = x0 | (y0 << 16);
        pk[13] = x1 | (y1 << 16);
        m = max(m, max(x0, x1));
    }
    #pragma unroll
    for (int off = 32; off > 0; off >>= 1)
        m = max(m, __shfl_down(m, off, 64));
    if ((t & 63) == 0) s_max[t >> 6] = m;
    __syncthreads();
    if (t == 0) {
        int mm = s_max[0];
        #pragma unroll
        for (int j = 1; j < 5; ++j) mm = max(mm, s_max[j]);
        s_mult = (mm + 1) >> 2;                // (max_x + 1) // k
    }
    __syncthreads();
    int mult = s_mult;

    #pragma unroll
    for (int j = 0; j < 14; ++j) {
        if (pk[j] >= 0) {                      // sentinel is the only negative
            int x = pk[j] & 0xffff, y = pk[j] >> 16;
            int seg = (x >> 2) + mult * (y >> 2);   // ref guarantees < LEN
            if (seg == myseg) {
                int s = (j < 12) ? 2 * (t + NT * (j >> 1)) + (j & 1)
                                 : 3840 + 2 * t + (j & 1);
                rows[atomicAdd(&s_cnt, 1)] = s;
            }
        }
    }
    __syncthreads();
    int cnt = s_cnt;

    // ---- Phase 2: stream-sum; thread t = float4 column t (t < 288) ----
    const float* hb = hidden + (size_t)b * NS * NH;
    if (t < NC) {
        vf4 a0 = 0.f, a1 = 0.f;
        int r = 0;
        for (; r + 7 < cnt; r += 8) {
            vf4 v0 = ((const vf4*)(hb + (size_t)rows[r + 0] * NH))[t];
            vf4 v1 = ((const vf4*)(hb + (size_t)rows[r + 1] * NH))[t];
            vf4 v2 = ((const vf4*)(hb + (size_t)rows[r + 2] * NH))[t];
            vf4 v3 = ((const vf4*)(hb + (size_t)rows[r + 3] * NH))[t];
            vf4 v4 = ((const vf4*)(hb + (size_t)rows[r + 4] * NH))[t];
            vf4 v5 = ((const vf4*)(hb + (size_t)rows[r + 5] * NH))[t];
            vf4 v6 = ((const vf4*)(hb + (size_t)rows[r + 6] * NH))[t];
            vf4 v7 = ((const vf4*)(hb + (size_t)rows[r + 7] * NH))[t];
            v0 += v1; v2 += v3; v4 += v5; v6 += v7;
            v0 += v2; v4 += v6;
            a0 += v0; a1 += v4;
        }
        for (; r < cnt; ++r)
            a0 += ((const vf4*)(hb + (size_t)rows[r] * NH))[t];
        a0 += a1;

        const float scale = 2.1213203435596424f;   // sqrt(1152) / 16
        ((vf4*)(out + (size_t)g * NH))[t] = a0 * scale;
    }
    if (t == 0) maskout[g] = (cnt > 0) ? 1.0f : 0.0f;
}

extern "C" void kernel_launch(void* const* d_in, const int* in_sizes, int n_in,
                              void* d_out, int out_size, void* d_ws, size_t ws_size,
                              hipStream_t stream) {
    const float* hidden = (const float*)d_in[0];
    const int*   patch  = (const int*)d_in[1];
    // d_in[2] (padding_positions) unused: S != LENGTH branch.
    float* out = (float*)d_out;
    float* maskout = out + (size_t)NB * LEN * NH;   // tuple: pooled then mask

    gvp_fused<<<NB * LEN, NT, 0, stream>>>(hidden, patch, out, maskout);
}